// Round 4
// baseline (562.157 us; speedup 1.0000x reference)
//
#include <hip/hip_runtime.h>
#include <hip/hip_bf16.h>
#include <cstdint>

#define N_ATOMS 100000
#define NFEAT   256
#define NMOL    1024
#define NU      6256    // 100096 / 16 atoms per unit

static constexpr float SCALE_C = 5.992277830325989f;
static constexpr float SHIFT_C = -406274.63784969115f;

typedef __attribute__((ext_vector_type(8))) short short8;    // bf16x8 MFMA operand
typedef __attribute__((ext_vector_type(4))) float float4_t;  // f32x4 accumulator

__device__ __forceinline__ unsigned short f2bf(float x) {
    union { float f; uint32_t u; } v; v.f = x;
    uint32_t r = (v.u + 0x7fffu + ((v.u >> 16) & 1u)) >> 16;
    return (unsigned short)r;
}

// pack two fp32 -> two bf16 (round-half-up) in one v_perm
__device__ __forceinline__ uint32_t pk(float lo, float hi) {
    union { float f; uint32_t u; } a, b; a.f = lo; b.f = hi;
    return __builtin_amdgcn_perm(b.u + 0x8000u, a.u + 0x8000u, 0x07060302u);
}

__device__ __forceinline__ float silu(float x) {
    return x / (1.0f + __expf(-x));
}

// async global->LDS, 16B/lane; LDS dest wave-uniform, lane i lands at +i*16B
__device__ __forceinline__ void async16(void* lds, const void* g) {
    __builtin_amdgcn_global_load_lds(
        (const __attribute__((address_space(1))) unsigned int*)(uintptr_t)g,
        (__attribute__((address_space(3))) unsigned int*)(uint32_t)(uintptr_t)lds,
        16, 0, 0);
}

// Global W image (written by prep, R4-verified layout):
//   pos = (k>>7)*32768 + n*128 + (((k>>3 & 15) ^ (n&15))&15)<<3 + (k&7)
// Col-half ch of plane p = contiguous 32 KB at p*32768 + ch*16384.
// LDS one 64 KB col-half: lpos = (kc>>4)*16384 + nl*128 + swz (nl&15 == n&15).
__device__ __forceinline__ short8 wfrag_h(const unsigned short* Wlds, int nl, int kc) {
    return *(const short8*)&Wlds[((kc >> 4) << 14) + nl * 128 +
                                 ((((kc & 15) ^ (nl & 15)) & 15) << 3)];
}

// ---------------------------------------------------------------------------
// Prep: W1,W2 fp32 [k][n] -> bf16 swizzled plane images; init out[] = SHIFT.
// ---------------------------------------------------------------------------
__global__ void prep(const float* __restrict__ W1, const float* __restrict__ W2,
                     unsigned short* __restrict__ W1i, unsigned short* __restrict__ W2i,
                     float* __restrict__ out) {
    int g = blockIdx.x * 256 + threadIdx.x;          // 0 .. 131071
    const float* W = (g < 65536) ? W1 : W2;
    unsigned short* Wi = (g < 65536) ? W1i : W2i;
    int idx = g & 65535;
    int k = idx >> 8, n = idx & 255;
    int kc = (k >> 3) & 15;
    int pos = ((k >> 7) << 15) + n * 128 + (((kc ^ (n & 15)) & 15) << 3) + (k & 7);
    Wi[pos] = f2bf(W[idx]);
    if (g < NMOL) out[g] = SHIFT_C;
}

// ---------------------------------------------------------------------------
// Layer 1: H1 = silu(A @ W1 + b1). Col-split (R10): 512 blocks x 512 thr,
// block (bslot,ch) owns cols ch*128..+127, 64 KB LDS W -> 2 blocks/CU,
// 16 waves/CU, acc[8]=32 regs, no spill.
// R11 lesson: R0 (8 waves) and R3 (16 waves) both 61us -> per-k-step
// depth-1 prefetch leaves waves ~80% stalled on load latency; wave count
// can't fix a per-step dependent stall. Fix: load the WHOLE unit's A
// (16 x dwordx4, independent) upfront -> ONE latency exposure per unit;
// steal the next unit while loads are in flight. Numerically identical.
// ---------------------------------------------------------------------------
__global__ __launch_bounds__(512, 4)
void gemm1(const float* __restrict__ A, const unsigned short* __restrict__ Wimg,
           const float* __restrict__ b1, unsigned short* __restrict__ H1) {
    __shared__ unsigned short Wlds[32768];   // 64 KB: one col-half, both k-planes
    __shared__ float b1L[128];
    __shared__ int uctr;

    const int tid = threadIdx.x;
    const int w = tid >> 6, lane = tid & 63;
    const int fl = lane & 15, qd = lane >> 4;
    const int ch = blockIdx.x >> 8;          // col-half 0/1
    const int bslot = blockIdx.x & 255;

    // stage 64 KB half: chunk c (512 shorts) -> plane p=c>>5, in-plane (c&31)*512
#pragma unroll
    for (int i = 0; i < 8; ++i) {
        int c = w * 8 + i;
        async16(&Wlds[c * 512],
                Wimg + ((c >> 5) << 15) + (ch << 14) + ((c & 31) << 9) + lane * 8);
    }
    if (tid < 32) ((float4*)b1L)[tid] = ((const float4*)(b1 + ch * 128))[tid];
    if (tid == 0) uctr = 0;
    __syncthreads();

    int t;
    { int tt = 0; if (lane == 0) tt = atomicAdd(&uctr, 1); t = __shfl(tt, 0); }

    for (;;) {
        const int u = bslot + (t << 8);           // stride-256 across slots
        if (u >= NU) break;

        const int row = u * 16 + fl;              // this lane's atom
        const bool valid = row < N_ATOMS;
        const float* ap = A + (size_t)row * 256 + qd * 8;

        // whole unit upfront: 16 independent dwordx4 (lane's 64 floats)
        float4 a[16];
        if (valid) {
#pragma unroll
            for (int i = 0; i < 16; ++i)
                a[i] = *(const float4*)(ap + (i >> 1) * 32 + (i & 1) * 4);
        } else {
#pragma unroll
            for (int i = 0; i < 16; ++i) a[i] = make_float4(0, 0, 0, 0);
        }

        // steal next unit while loads are in flight
        { int tt = 0; if (lane == 0) tt = atomicAdd(&uctr, 1); t = __shfl(tt, 0); }

        float4_t acc[8] = {};
#pragma unroll
        for (int s = 0; s < 8; ++s) {
            const float4 c0 = a[s * 2], c1 = a[s * 2 + 1];
            union { uint32_t u4[4]; short8 s8; } cv;
            cv.u4[0] = pk(c0.x, c0.y); cv.u4[1] = pk(c0.z, c0.w);
            cv.u4[2] = pk(c1.x, c1.y); cv.u4[3] = pk(c1.z, c1.w);
            const int kc = s * 4 + qd;
#pragma unroll
            for (int j = 0; j < 8; ++j) {
                short8 wf = wfrag_h(Wlds, j * 16 + fl, kc);
                acc[j] = __builtin_amdgcn_mfma_f32_16x16x32_bf16(wf, cv.s8, acc[j], 0, 0, 0);
            }
        }

        if (valid) {
#pragma unroll
            for (int j = 0; j < 8; ++j) {
                int nl = j * 16 + qd * 4;          // local col
                float4 b4 = *(const float4*)&b1L[nl];
                uint2 o;
                o.x = pk(silu(acc[j][0] + b4.x), silu(acc[j][1] + b4.y));
                o.y = pk(silu(acc[j][2] + b4.z), silu(acc[j][3] + b4.w));
                *(uint2*)&H1[(size_t)row * 256 + ch * 128 + nl] = o;
            }
        }
    }
}

// ---------------------------------------------------------------------------
// Layer 2+3+pool: out[mol] += SCALE*(silu(H1@W2+b2).W3 + b3). Col-split
// partial W3-dot (additive across halves); b3 added only by half 0.
// R11: whole unit's H1 (8 x short8) loaded upfront, steal-ahead overlap.
// Pooling via per-block LDS bucket[1024], one global atomic per nonzero
// bucket at the end.
// ---------------------------------------------------------------------------
__global__ __launch_bounds__(512, 4)
void gemm2(const unsigned short* __restrict__ H1, const unsigned short* __restrict__ Wimg,
           const float* __restrict__ b2, const float* __restrict__ W3,
           const float* __restrict__ b3, const int* __restrict__ batch,
           float* __restrict__ out) {
    __shared__ unsigned short Wlds[32768];   // 64 KB
    __shared__ float bucket[NMOL];           // 4 KB
    __shared__ int uctr;

    const int tid = threadIdx.x;
    const int w = tid >> 6, lane = tid & 63;
    const int fl = lane & 15, qd = lane >> 4;
    const int ch = blockIdx.x >> 8;
    const int bslot = blockIdx.x & 255;

#pragma unroll
    for (int i = 0; i < 8; ++i) {
        int c = w * 8 + i;
        async16(&Wlds[c * 512],
                Wimg + ((c >> 5) << 15) + (ch << 14) + ((c & 31) << 9) + lane * 8);
    }
    bucket[tid] = 0.0f;
    bucket[tid + 512] = 0.0f;
    if (tid == 0) uctr = 0;
    __syncthreads();

    const float b3v = (ch == 0) ? b3[0] : 0.0f;   // add b3 once per atom
    float bbv[8], w3v[8];
#pragma unroll
    for (int nt = 0; nt < 8; ++nt) {
        bbv[nt] = b2[ch * 128 + nt * 16 + fl];
        w3v[nt] = W3[ch * 128 + nt * 16 + fl];
    }

    int t;
    { int tt = 0; if (lane == 0) tt = atomicAdd(&uctr, 1); t = __shfl(tt, 0); }

    for (;;) {
        const int u = bslot + (t << 8);
        if (u >= NU) break;

        const int ubase = u * 16;
        const int row = ubase + fl;
        const bool valid = row < N_ATOMS;
        const unsigned short* hp = H1 + (size_t)row * 256 + qd * 8;

        // whole unit upfront: 8 independent 16B loads
        short8 h[8];
        if (valid) {
#pragma unroll
            for (int s = 0; s < 8; ++s) h[s] = *(const short8*)(hp + s * 32);
        } else {
#pragma unroll
            for (int s = 0; s < 8; ++s) h[s] = (short8){0, 0, 0, 0, 0, 0, 0, 0};
        }

        { int tt = 0; if (lane == 0) tt = atomicAdd(&uctr, 1); t = __shfl(tt, 0); }

        float4_t acc[8] = {};
#pragma unroll
        for (int s = 0; s < 8; ++s) {
            const int kc = s * 4 + qd;
#pragma unroll
            for (int nt = 0; nt < 8; ++nt) {
                short8 wf = wfrag_h(Wlds, nt * 16 + fl, kc);
                acc[nt] = __builtin_amdgcn_mfma_f32_16x16x32_bf16(h[s], wf, acc[nt], 0, 0, 0);
            }
        }

        // acc[nt][r]: atom = ubase + qd*4 + r, col = ch*128 + nt*16 + fl
        float rs[4] = {};
#pragma unroll
        for (int nt = 0; nt < 8; ++nt)
#pragma unroll
            for (int r = 0; r < 4; ++r)
                rs[r] += silu(acc[nt][r] + bbv[nt]) * w3v[nt];
#pragma unroll
        for (int r = 0; r < 4; ++r) {
            float v = rs[r];
            v += __shfl_xor(v, 1);
            v += __shfl_xor(v, 2);
            v += __shfl_xor(v, 4);
            v += __shfl_xor(v, 8);
            rs[r] = v;
        }
        if (fl == 0) {
            int atom0 = ubase + qd * 4;
            if (atom0 < N_ATOMS) {   // atom0 % 4 == 0 -> all 4 rows valid
                int4 mb = *(const int4*)&batch[atom0];
                float v0 = rs[0] + b3v, v1 = rs[1] + b3v,
                      v2 = rs[2] + b3v, v3 = rs[3] + b3v;
                if (mb.x == mb.w) {
                    atomicAdd(&bucket[mb.x], (v0 + v1) + (v2 + v3));
                } else {
                    atomicAdd(&bucket[mb.x], v0);
                    atomicAdd(&bucket[mb.y], v1);
                    atomicAdd(&bucket[mb.z], v2);
                    atomicAdd(&bucket[mb.w], v3);
                }
            }
        }
    }
    __syncthreads();
#pragma unroll
    for (int i = 0; i < 2; ++i) {
        int m = tid + i * 512;
        float v = bucket[m];
        if (v != 0.0f) atomicAdd(&out[m], v * SCALE_C);
    }
}

// ---------------------------------------------------------------------------
extern "C" void kernel_launch(void* const* d_in, const int* in_sizes, int n_in,
                              void* d_out, int out_size, void* d_ws, size_t ws_size,
                              hipStream_t stream) {
    const float* A     = (const float*)d_in[0];
    const int*   batch = (const int*)d_in[1];
    const float* W1    = (const float*)d_in[2];
    const float* b1    = (const float*)d_in[3];
    const float* W2    = (const float*)d_in[4];
    const float* b2    = (const float*)d_in[5];
    const float* W3    = (const float*)d_in[6];
    const float* b3    = (const float*)d_in[7];
    float* out = (float*)d_out;

    unsigned short* H1  = (unsigned short*)d_ws;            // 100096*256 bf16
    unsigned short* W1i = H1 + (size_t)100096 * NFEAT;      // 65536 shorts
    unsigned short* W2i = W1i + 65536;                      // 65536 shorts

    prep<<<dim3(512), 256, 0, stream>>>(W1, W2, W1i, W2i, out);
    gemm1<<<dim3(512), 512, 0, stream>>>(A, W1i, b1, H1);
    gemm2<<<dim3(512), 512, 0, stream>>>(H1, W2i, b2, W3, b3, batch, out);
}